// Round 1
// baseline (509.059 us; speedup 1.0000x reference)
//
#include <hip/hip_runtime.h>
#include <math.h>

#define WW   160
#define HHH  160
#define DDD  160
#define NBATCH 4
#define VOL  (160*160*160)      // 4,096,000
#define PLANE (160*160)

#define C1f 0.0001f
#define C2f 0.0009f

struct Gw { float g[11]; };

// ---------------- Pass 1: conv along W (innermost), build 5 channels ----------------
// block 256 = 4 rows x 64 lanes; grid (wchunk=3, rowgroup=6400)
__global__ __launch_bounds__(256) void k_convw(
    const float* __restrict__ x, const float* __restrict__ y,
    float* __restrict__ A, Gw gw)
{
    __shared__ float sx[4][80];
    __shared__ float sy[4][80];
    const int lane = threadIdx.x & 63;
    const int r    = threadIdx.x >> 6;
    const int w0   = blockIdx.x * 64;
    const int row  = blockIdx.y * 4 + r;      // row = d*160 + h, < 25600

    const float* xr = x + (size_t)row * WW;
    const float* yr = y + (size_t)row * WW;

    // stage 74 floats per row (halo 5 each side of 64-wide chunk)
    for (int t = lane; t < 74; t += 64) {
        int gwi = w0 - 5 + t;
        bool ok = (gwi >= 0) && (gwi < WW);
        int ci = ok ? gwi : 0;
        sx[r][t] = ok ? xr[ci] : 0.f;
        sy[r][t] = ok ? yr[ci] : 0.f;
    }
    __syncthreads();

    float a0=0.f,a1=0.f,a2=0.f,a3=0.f,a4=0.f;
#pragma unroll
    for (int k = 0; k < 11; ++k) {
        float xa = sx[r][lane + k];
        float ya = sy[r][lane + k];
        float g  = gw.g[k];
        a0 += g * xa;
        a1 += g * ya;
        a2 += g * (xa * xa);
        a3 += g * (ya * ya);
        a4 += g * (xa * ya);
    }
    int w = w0 + lane;
    if (w < WW) {
        size_t o = (size_t)row * WW + w;
        A[o            ] = a0;
        A[o + 1*(size_t)VOL] = a1;
        A[o + 2*(size_t)VOL] = a2;
        A[o + 3*(size_t)VOL] = a3;
        A[o + 4*(size_t)VOL] = a4;
    }
}

// ---------------- Pass 2: conv along H, register ring buffer ----------------
// block 64 lanes (w); grid (wchunk=3, hrun=4 [runs of 40], d=160)
__global__ __launch_bounds__(64) void k_convh(
    const float* __restrict__ A, float* __restrict__ B, Gw gw)
{
    const int lane = threadIdx.x;
    const int w  = blockIdx.x * 64 + lane;
    const int h0 = blockIdx.y * 40;
    const int d  = blockIdx.z;
    if (w >= WW) return;   // no barriers below — early return safe

    const float* base = A + (size_t)d * PLANE + w;
    float*       outb = B + (size_t)d * PLANE + w;

    float ring[5][11];
#pragma unroll
    for (int i = 0; i < 50; ++i) {
        int h = h0 - 5 + i;
        bool ok = (h >= 0) && (h < HHH);
        int hc = ok ? h : 0;
        size_t idx = (size_t)hc * WW;
#pragma unroll
        for (int c = 0; c < 5; ++c) {
            float v = base[idx + (size_t)c * VOL];
            ring[c][i % 11] = ok ? v : 0.f;
        }
        if (i >= 10) {
            const int j = i - 10;          // output row h0+j
            float acc[5] = {0.f,0.f,0.f,0.f,0.f};
#pragma unroll
            for (int k = 0; k < 11; ++k) {
                float g = gw.g[k];
#pragma unroll
                for (int c = 0; c < 5; ++c)
                    acc[c] += g * ring[c][(j + k) % 11];
            }
            size_t oi = (size_t)(h0 + j) * WW;
#pragma unroll
            for (int c = 0; c < 5; ++c)
                outb[oi + (size_t)c * VOL] = acc[c];
        }
    }
}

// ---------------- Pass 3: conv along D + SSIM + reduction ----------------
// block 64 lanes (w); grid (wchunk=3, h=160, drun=4 [runs of 40])
__global__ __launch_bounds__(64) void k_convd_ssim(
    const float* __restrict__ B, double* __restrict__ accum, Gw gw)
{
    const int lane = threadIdx.x;
    const int w  = blockIdx.x * 64 + lane;
    const int h  = blockIdx.y;
    const int d0 = blockIdx.z * 40;

    float lsum = 0.f;
    if (w < WW) {
        const float* base = B + (size_t)h * WW + w;
        float ring[5][11];
#pragma unroll
        for (int i = 0; i < 50; ++i) {
            int d = d0 - 5 + i;
            bool ok = (d >= 0) && (d < DDD);
            int dc = ok ? d : 0;
            size_t idx = (size_t)dc * PLANE;
#pragma unroll
            for (int c = 0; c < 5; ++c) {
                float v = base[idx + (size_t)c * VOL];
                ring[c][i % 11] = ok ? v : 0.f;
            }
            if (i >= 10) {
                const int j = i - 10;
                float acc[5] = {0.f,0.f,0.f,0.f,0.f};
#pragma unroll
                for (int k = 0; k < 11; ++k) {
                    float g = gw.g[k];
#pragma unroll
                    for (int c = 0; c < 5; ++c)
                        acc[c] += g * ring[c][(j + k) % 11];
                }
                float mu1 = acc[0], mu2 = acc[1];
                float e11 = acc[2], e22 = acc[3], e12 = acc[4];
                float m11 = mu1 * mu2;
                float num = (2.f * m11 + C1f) * (2.f * (e12 - m11) + C2f);
                float den = (mu1*mu1 + mu2*mu2 + C1f) *
                            ((e11 - mu1*mu1) + (e22 - mu2*mu2) + C2f);
                lsum += num / den;
            }
        }
    }
    // wave64 reduction
#pragma unroll
    for (int off = 32; off > 0; off >>= 1)
        lsum += __shfl_down(lsum, off, 64);
    if (lane == 0)
        atomicAdd(accum, (double)lsum);
}

__global__ void k_final(const double* __restrict__ accum, float* __restrict__ out)
{
    out[0] = (float)(1.0 - accum[0] / (double)((double)NBATCH * (double)VOL));
}

extern "C" void kernel_launch(void* const* d_in, const int* in_sizes, int n_in,
                              void* d_out, int out_size, void* d_ws, size_t ws_size,
                              hipStream_t stream)
{
    const float* img1 = (const float*)d_in[0];
    const float* img2 = (const float*)d_in[1];
    float* out = (float*)d_out;

    char* ws = (char*)d_ws;
    float* A = (float*)ws;                          // 5*VOL floats = 81.92 MB
    float* B = A + 5 * (size_t)VOL;                 // 5*VOL floats = 81.92 MB
    double* accum = (double*)(ws + 10 * (size_t)VOL * sizeof(float)); // 8 B

    // Gaussian window, computed on host in double, normalized
    Gw gw;
    {
        double gd[11], s = 0.0;
        for (int i = 0; i < 11; ++i) {
            double t = (double)(i - 5);
            gd[i] = exp(-(t * t) / (2.0 * 1.5 * 1.5));
            s += gd[i];
        }
        for (int i = 0; i < 11; ++i) gw.g[i] = (float)(gd[i] / s);
    }

    hipMemsetAsync(accum, 0, sizeof(double), stream);

    for (int n = 0; n < NBATCH; ++n) {
        const float* x = img1 + (size_t)n * VOL;
        const float* y = img2 + (size_t)n * VOL;
        k_convw<<<dim3(3, 6400, 1), 256, 0, stream>>>(x, y, A, gw);
        k_convh<<<dim3(3, 4, 160), 64, 0, stream>>>(A, B, gw);
        k_convd_ssim<<<dim3(3, 160, 4), 64, 0, stream>>>(B, accum, gw);
    }
    k_final<<<1, 1, 0, stream>>>(accum, out);
}